// Round 17
// baseline (440.964 us; speedup 1.0000x reference)
//
#include <hip/hip_runtime.h>
#include <hip/hip_bf16.h>

#define N_NODES   100000
#define N_EDGES   1600000
#define DIM       64
#define OUT_DIM   10
#define N_GRAPHS  1000
#define BN_EPS    1e-5f
#define NBUCKET   391          // ceil(N_NODES / 256)
#define TILE_E    6400
#define NT        250          // N_EDGES / TILE_E (exact)

typedef __hip_bfloat16 bf16;
__device__ __forceinline__ float b2f(bf16 v) { return __bfloat162float(v); }

typedef __attribute__((ext_vector_type(8))) short short8;   // 8 bf16 = 4 VGPRs
typedef __attribute__((ext_vector_type(4))) float floatx4;  // MFMA C/D

__device__ __forceinline__ short f2bs(float f) {
    union { bf16 h; short s; } u;
    u.h = __float2bfloat16(f);
    return u.s;
}

// ---- phase 1: per-tile bucket histogram (LDS atomics only) ----

__global__ void __launch_bounds__(256) k_bucket_count(const int* __restrict__ dst,
                                                      int* __restrict__ tileCnt, int e) {
    __shared__ int hcnt[NBUCKET];
    int t = blockIdx.x, tid = threadIdx.x;
    for (int b = tid; b < NBUCKET; b += 256) hcnt[b] = 0;
    __syncthreads();
    int ibase = t * TILE_E;
    for (int j = 0; j < TILE_E; j += 256) {
        int i = ibase + j + tid;
        if (i < e) atomicAdd(&hcnt[dst[i] >> 8], 1);
    }
    __syncthreads();
    for (int b = tid; b < NBUCKET; b += 256) tileCnt[b * NT + t] = hcnt[b];
}

// ---- phase 2a: per-bucket exclusive scan over tiles (in-place) + bucket totals ----

__global__ void __launch_bounds__(256) k_tile_scan(int* __restrict__ tileCnt,
                                                   int* __restrict__ bucketTot) {
    __shared__ int tmp[256];
    int b = blockIdx.x, tid = threadIdx.x;
    int v = (tid < NT) ? tileCnt[b * NT + tid] : 0;
    tmp[tid] = v;
    __syncthreads();
    for (int off = 1; off < 256; off <<= 1) {
        int t = (tid >= off) ? tmp[tid - off] : 0;
        __syncthreads();
        tmp[tid] += t;
        __syncthreads();
    }
    if (tid < NT) tileCnt[b * NT + tid] = tmp[tid] - v;   // exclusive over tiles
    if (tid == 255) bucketTot[b] = tmp[255];
}

// ---- phase 2b: single-block exclusive scan of bucket totals (nb <= 512) ----

__global__ void k_scan_sums(int* __restrict__ bsums, int nb) {
    __shared__ int tmp[512];
    int tid = threadIdx.x;
    int v = (tid < nb) ? bsums[tid] : 0;
    tmp[tid] = v;
    __syncthreads();
    for (int off = 1; off < 512; off <<= 1) {
        int t = (tid >= off) ? tmp[tid - off] : 0;
        __syncthreads();
        tmp[tid] += t;
        __syncthreads();
    }
    if (tid < nb) bsums[tid] = tmp[tid] - v;      // exclusive -> bucket base
}

// ---- phase 3: write edges into per-tile reserved ranges (dense, no global atomics) ----

__global__ void __launch_bounds__(256) k_bucket_write(
    const int* __restrict__ src, const int* __restrict__ dst,
    const int* __restrict__ bbase, const int* __restrict__ tilePrefix,
    unsigned int* __restrict__ packed, int e) {
    __shared__ int hbase[NBUCKET];
    __shared__ int hcur[NBUCKET];
    int t = blockIdx.x, tid = threadIdx.x;
    for (int b = tid; b < NBUCKET; b += 256) {
        hbase[b] = bbase[b] + tilePrefix[b * NT + t];
        hcur[b] = 0;
    }
    __syncthreads();
    int ibase = t * TILE_E;
    for (int j = 0; j < TILE_E; j += 256) {
        int i = ibase + j + tid;
        if (i < e) {
            int d  = dst[i];
            int bb = d >> 8;
            int pos = hbase[bb] + atomicAdd(&hcur[bb], 1);
            packed[pos] = ((unsigned int)src[i] << 8) | (unsigned int)(d & 255);
        }
    }
}

// ---- phase 4: within-bucket counting sort; also emits offs/hist/dinv ----

__global__ void __launch_bounds__(256) k_local_sort(
    const unsigned int* __restrict__ packed, const int* __restrict__ bbase,
    int* __restrict__ ssrc, int* __restrict__ offs, int* __restrict__ hist,
    float* __restrict__ dinv, int n, int e) {
    __shared__ int tmp[256];
    __shared__ int noffs[256];
    __shared__ int ncur[256];
    int b = blockIdx.x, tid = threadIdx.x;
    int base   = b << 8;
    int estart = bbase[b];
    int eend   = (b + 1 < NBUCKET) ? bbase[b + 1] : e;

    ncur[tid] = 0;                 // reuse as per-node counter first
    __syncthreads();
    for (int i = estart + tid; i < eend; i += 256)
        atomicAdd(&ncur[packed[i] & 255u], 1);
    __syncthreads();
    int v = ncur[tid];             // degree of node base+tid
    tmp[tid] = v;
    __syncthreads();
    for (int off = 1; off < 256; off <<= 1) {
        int t = (tid >= off) ? tmp[tid - off] : 0;
        __syncthreads();
        tmp[tid] += t;
        __syncthreads();
    }
    int mystart = estart + tmp[tid] - v;   // exclusive within bucket
    noffs[tid] = mystart;
    ncur[tid]  = 0;
    int node = base + tid;
    if (node < n) {
        offs[node] = mystart;
        hist[node] = v;
        dinv[node] = rsqrtf((float)(v + 1));   // +1 self loop
    }
    __syncthreads();
    for (int i = estart + tid; i < eend; i += 256) {
        unsigned int p = packed[i];
        int d = p & 255u;
        int pos = noffs[d] + atomicAdd(&ncur[d], 1);
        ssrc[pos] = (int)(p >> 8);
    }
}

// ------- MFMA matmul (layer 0 only): Hs[row] = dinv[row] * (x[row] @ W) -> bf16 -------
// Verified layouts (m89/m91/m120): A[m=lane&15][k=quad*8+j] (contiguous 16B),
// B[k=quad*8+j][n=lane&15], C/D[row=quad*4+reg][col=lane&15].

__global__ void __launch_bounds__(256) k_matmul_mfma(
    const float* __restrict__ hf, const float* __restrict__ W,
    const float* __restrict__ dinv, bf16* __restrict__ Hs, int ntiles, int nwaves)
{
    int wid  = (blockIdx.x * blockDim.x + threadIdx.x) >> 6;
    int lane = threadIdx.x & 63;
    if (wid >= ntiles) return;
    int quad = lane >> 4, m16 = lane & 15;

    short8 Bfrag[4][2];
#pragma unroll
    for (int t = 0; t < 4; t++)
#pragma unroll
        for (int h = 0; h < 2; h++) {
            short8 b;
#pragma unroll
            for (int j = 0; j < 8; j++)
                b[j] = f2bs(W[(h * 32 + quad * 8 + j) * 64 + t * 16 + m16]);
            Bfrag[t][h] = b;
        }

    for (int tile = wid; tile < ntiles; tile += nwaves) {
        int row0 = tile * 16;
        short8 A0, A1;
        const float* base = hf + (size_t)(row0 + m16) * 64 + quad * 8;
#pragma unroll
        for (int j = 0; j < 8; j++) {
            A0[j] = f2bs(base[j]);
            A1[j] = f2bs(base[32 + j]);
        }

        floatx4 acc[4];
#pragma unroll
        for (int t = 0; t < 4; t++) {
            floatx4 c = {0.f, 0.f, 0.f, 0.f};
            c = __builtin_amdgcn_mfma_f32_16x16x32_bf16(A0, Bfrag[t][0], c, 0, 0, 0);
            c = __builtin_amdgcn_mfma_f32_16x16x32_bf16(A1, Bfrag[t][1], c, 0, 0, 0);
            acc[t] = c;
        }

#pragma unroll
        for (int r = 0; r < 4; r++) {
            int row = row0 + quad * 4 + r;
            float dn = dinv[row];
#pragma unroll
            for (int t = 0; t < 4; t++)
                Hs[(size_t)row * 64 + t * 16 + m16] = __float2bfloat16(dn * acc[t][r]);
        }
    }
}

// ------- FUSED gather + BN + relu + JK-pool + MFMA next-layer matmul -------
// Block = 4 waves = one 16-node tile per iteration. Each wave gathers 4 nodes
// (proven 16-unroll inner loop, scalar index loads), stages val as bf16 in a
// padded LDS tile (16 x 72 shorts: A-frag ds_read_b128 -> 2-way banks, free),
// then each wave MFMAs its own 16-col slice (B-frags = 8 VGPRs, avoiding
// R13's 64-VGPR cliff). Removes the hbuf round-trip (77MB streaming) and 3
// dispatches. HsIn/HsOut ping-pong avoids the overwrite race.

__global__ void __launch_bounds__(256) k_gather_mm(
    const bf16* __restrict__ HsIn, const int* __restrict__ ssrc,
    const int* __restrict__ offs, const int* __restrict__ hist,
    const float* __restrict__ dinv, const float* __restrict__ bias,
    const float* __restrict__ gamma, const float* __restrict__ beta,
    const float* __restrict__ mean, const float* __restrict__ var,
    const int* __restrict__ batch, const float* __restrict__ W,
    bf16* __restrict__ HsOut, float* __restrict__ pooled, int layer, int ntiles)
{
    __shared__ short tile[16][72];
    int wv   = threadIdx.x >> 6;         // wave = col-tile owner
    int lane = threadIdx.x & 63;
    int quad = lane >> 4, m16 = lane & 15;

    float P = gamma[lane] * rsqrtf(var[lane] + BN_EPS);
    float Q = (bias[lane] - mean[lane]) * P + beta[lane];

    short8 B0, B1;                       // this wave's 2 B-frags (8 VGPRs)
#pragma unroll
    for (int j = 0; j < 8; j++) {
        B0[j] = f2bs(W[(quad * 8 + j) * 64 + wv * 16 + m16]);
        B1[j] = f2bs(W[(32 + quad * 8 + j) * 64 + wv * 16 + m16]);
    }

    for (int t = blockIdx.x; t < ntiles; t += gridDim.x) {
        int row0 = t * 16;
#pragma unroll
        for (int j2 = 0; j2 < 4; j2++) {
            int node = row0 + wv * 4 + j2;
            int start = __builtin_amdgcn_readfirstlane(offs[node]);
            int cnt   = __builtin_amdgcn_readfirstlane(hist[node]);

            float acc = b2f(HsIn[node * 64 + lane]);   // self-loop (pre-scaled)
            int i = 0;
            for (; i + 15 < cnt; i += 16) {
                int s0  = ssrc[start + i];
                int s1  = ssrc[start + i + 1];
                int s2  = ssrc[start + i + 2];
                int s3  = ssrc[start + i + 3];
                int s4  = ssrc[start + i + 4];
                int s5  = ssrc[start + i + 5];
                int s6  = ssrc[start + i + 6];
                int s7  = ssrc[start + i + 7];
                int s8  = ssrc[start + i + 8];
                int s9  = ssrc[start + i + 9];
                int s10 = ssrc[start + i + 10];
                int s11 = ssrc[start + i + 11];
                int s12 = ssrc[start + i + 12];
                int s13 = ssrc[start + i + 13];
                int s14 = ssrc[start + i + 14];
                int s15 = ssrc[start + i + 15];
                float v0  = b2f(HsIn[s0  * 64 + lane]);
                float v1  = b2f(HsIn[s1  * 64 + lane]);
                float v2  = b2f(HsIn[s2  * 64 + lane]);
                float v3  = b2f(HsIn[s3  * 64 + lane]);
                float v4  = b2f(HsIn[s4  * 64 + lane]);
                float v5  = b2f(HsIn[s5  * 64 + lane]);
                float v6  = b2f(HsIn[s6  * 64 + lane]);
                float v7  = b2f(HsIn[s7  * 64 + lane]);
                float v8  = b2f(HsIn[s8  * 64 + lane]);
                float v9  = b2f(HsIn[s9  * 64 + lane]);
                float v10 = b2f(HsIn[s10 * 64 + lane]);
                float v11 = b2f(HsIn[s11 * 64 + lane]);
                float v12 = b2f(HsIn[s12 * 64 + lane]);
                float v13 = b2f(HsIn[s13 * 64 + lane]);
                float v14 = b2f(HsIn[s14 * 64 + lane]);
                float v15 = b2f(HsIn[s15 * 64 + lane]);
                acc += (((v0 + v1) + (v2 + v3)) + ((v4 + v5) + (v6 + v7))) +
                       (((v8 + v9) + (v10 + v11)) + ((v12 + v13) + (v14 + v15)));
            }
            for (; i + 3 < cnt; i += 4) {
                int s0 = ssrc[start + i];
                int s1 = ssrc[start + i + 1];
                int s2 = ssrc[start + i + 2];
                int s3 = ssrc[start + i + 3];
                float v0 = b2f(HsIn[s0 * 64 + lane]);
                float v1 = b2f(HsIn[s1 * 64 + lane]);
                float v2 = b2f(HsIn[s2 * 64 + lane]);
                float v3 = b2f(HsIn[s3 * 64 + lane]);
                acc += (v0 + v1) + (v2 + v3);
            }
            for (; i < cnt; i++)
                acc += b2f(HsIn[ssrc[start + i] * 64 + lane]);

            float val = fmaxf(dinv[node] * acc * P + Q, 0.f);
            atomicAdd(&pooled[batch[node] * 256 + layer * 64 + lane], val);
            tile[wv * 4 + j2][lane] = f2bs(val);
        }
        __syncthreads();

        short8 A0 = *(const short8*)&tile[m16][quad * 8];
        short8 A1 = *(const short8*)&tile[m16][32 + quad * 8];
        floatx4 c = {0.f, 0.f, 0.f, 0.f};
        c = __builtin_amdgcn_mfma_f32_16x16x32_bf16(A0, B0, c, 0, 0, 0);
        c = __builtin_amdgcn_mfma_f32_16x16x32_bf16(A1, B1, c, 0, 0, 0);
#pragma unroll
        for (int r = 0; r < 4; r++) {
            int row = row0 + quad * 4 + r;
            HsOut[(size_t)row * 64 + wv * 16 + m16] =
                __float2bfloat16(dinv[row] * c[r]);
        }
        __syncthreads();   // protect tile before next iteration overwrites
    }
}

// ------- lean gather for the last layer (R15-proven, no matmul) -------

__global__ void __launch_bounds__(256) k_gather(
    const bf16* __restrict__ Hs, const int* __restrict__ ssrc,
    const int* __restrict__ offs, const int* __restrict__ hist,
    const float* __restrict__ dinv, const float* __restrict__ bias,
    const float* __restrict__ gamma, const float* __restrict__ beta,
    const float* __restrict__ mean, const float* __restrict__ var,
    const int* __restrict__ batch, float* __restrict__ pooled,
    int layer, int n, int nwaves)
{
    int wid  = (blockIdx.x * blockDim.x + threadIdx.x) >> 6;
    int lane = threadIdx.x & 63;

    float P = gamma[lane] * rsqrtf(var[lane] + BN_EPS);
    float Q = (bias[lane] - mean[lane]) * P + beta[lane];

    for (int node = wid; node < n; node += nwaves) {
        int start = __builtin_amdgcn_readfirstlane(offs[node]);
        int cnt   = __builtin_amdgcn_readfirstlane(hist[node]);

        float acc = b2f(Hs[node * 64 + lane]);
        int i = 0;
        for (; i + 15 < cnt; i += 16) {
            int s0  = ssrc[start + i];
            int s1  = ssrc[start + i + 1];
            int s2  = ssrc[start + i + 2];
            int s3  = ssrc[start + i + 3];
            int s4  = ssrc[start + i + 4];
            int s5  = ssrc[start + i + 5];
            int s6  = ssrc[start + i + 6];
            int s7  = ssrc[start + i + 7];
            int s8  = ssrc[start + i + 8];
            int s9  = ssrc[start + i + 9];
            int s10 = ssrc[start + i + 10];
            int s11 = ssrc[start + i + 11];
            int s12 = ssrc[start + i + 12];
            int s13 = ssrc[start + i + 13];
            int s14 = ssrc[start + i + 14];
            int s15 = ssrc[start + i + 15];
            float v0  = b2f(Hs[s0  * 64 + lane]);
            float v1  = b2f(Hs[s1  * 64 + lane]);
            float v2  = b2f(Hs[s2  * 64 + lane]);
            float v3  = b2f(Hs[s3  * 64 + lane]);
            float v4  = b2f(Hs[s4  * 64 + lane]);
            float v5  = b2f(Hs[s5  * 64 + lane]);
            float v6  = b2f(Hs[s6  * 64 + lane]);
            float v7  = b2f(Hs[s7  * 64 + lane]);
            float v8  = b2f(Hs[s8  * 64 + lane]);
            float v9  = b2f(Hs[s9  * 64 + lane]);
            float v10 = b2f(Hs[s10 * 64 + lane]);
            float v11 = b2f(Hs[s11 * 64 + lane]);
            float v12 = b2f(Hs[s12 * 64 + lane]);
            float v13 = b2f(Hs[s13 * 64 + lane]);
            float v14 = b2f(Hs[s14 * 64 + lane]);
            float v15 = b2f(Hs[s15 * 64 + lane]);
            acc += (((v0 + v1) + (v2 + v3)) + ((v4 + v5) + (v6 + v7))) +
                   (((v8 + v9) + (v10 + v11)) + ((v12 + v13) + (v14 + v15)));
        }
        for (; i + 7 < cnt; i += 8) {
            int s0 = ssrc[start + i];
            int s1 = ssrc[start + i + 1];
            int s2 = ssrc[start + i + 2];
            int s3 = ssrc[start + i + 3];
            int s4 = ssrc[start + i + 4];
            int s5 = ssrc[start + i + 5];
            int s6 = ssrc[start + i + 6];
            int s7 = ssrc[start + i + 7];
            float v0 = b2f(Hs[s0 * 64 + lane]);
            float v1 = b2f(Hs[s1 * 64 + lane]);
            float v2 = b2f(Hs[s2 * 64 + lane]);
            float v3 = b2f(Hs[s3 * 64 + lane]);
            float v4 = b2f(Hs[s4 * 64 + lane]);
            float v5 = b2f(Hs[s5 * 64 + lane]);
            float v6 = b2f(Hs[s6 * 64 + lane]);
            float v7 = b2f(Hs[s7 * 64 + lane]);
            acc += ((v0 + v1) + (v2 + v3)) + ((v4 + v5) + (v6 + v7));
        }
        for (; i + 3 < cnt; i += 4) {
            int s0 = ssrc[start + i];
            int s1 = ssrc[start + i + 1];
            int s2 = ssrc[start + i + 2];
            int s3 = ssrc[start + i + 3];
            float v0 = b2f(Hs[s0 * 64 + lane]);
            float v1 = b2f(Hs[s1 * 64 + lane]);
            float v2 = b2f(Hs[s2 * 64 + lane]);
            float v3 = b2f(Hs[s3 * 64 + lane]);
            acc += (v0 + v1) + (v2 + v3);
        }
        for (; i < cnt; i++)
            acc += b2f(Hs[ssrc[start + i] * 64 + lane]);

        float val = fmaxf(dinv[node] * acc * P + Q, 0.f);
        atomicAdd(&pooled[batch[node] * 256 + layer * 64 + lane], val);
    }
}

// ---------------- final MLP: relu(pooled@W1+b1)@W2+b2 -> f32 out ----------------

__global__ void k_mlp(const float* __restrict__ pooled, const float* __restrict__ W1,
                      const float* __restrict__ b1, const float* __restrict__ W2,
                      const float* __restrict__ b2, float* __restrict__ out) {
    __shared__ float p[256];
    __shared__ float t[64];
    int g = blockIdx.x;
    int tid = threadIdx.x;    // 64 threads
    for (int i = tid; i < 256; i += 64) p[i] = pooled[g * 256 + i];
    __syncthreads();
    float acc = b1[tid];
    for (int k = 0; k < 256; k++)
        acc = fmaf(p[k], W1[k * 64 + tid], acc);
    t[tid] = fmaxf(acc, 0.f);
    __syncthreads();
    if (tid < OUT_DIM) {
        float o = b2[tid];
#pragma unroll
        for (int d = 0; d < 64; d++)
            o = fmaf(t[d], W2[d * OUT_DIM + tid], o);
        out[g * OUT_DIM + tid] = o;
    }
}

// ---------------- host launch ----------------

extern "C" void kernel_launch(void* const* d_in, const int* in_sizes, int n_in,
                              void* d_out, int out_size, void* d_ws, size_t ws_size,
                              hipStream_t stream) {
    const float* x          = (const float*)d_in[0];
    const int*   edge_index = (const int*)d_in[1];
    const int*   batch      = (const int*)d_in[2];
    const float* Wl[4] = { (const float*)d_in[4], (const float*)d_in[6],
                           (const float*)d_in[8], (const float*)d_in[10] };
    const float* bl[4] = { (const float*)d_in[5], (const float*)d_in[7],
                           (const float*)d_in[9], (const float*)d_in[11] };
    const float* bn_gamma = (const float*)d_in[12];
    const float* bn_beta  = (const float*)d_in[13];
    const float* bn_mean  = (const float*)d_in[14];
    const float* bn_var   = (const float*)d_in[15];
    const float* lin1_W = (const float*)d_in[16];
    const float* lin1_b = (const float*)d_in[17];
    const float* lin2_W = (const float*)d_in[18];
    const float* lin2_b = (const float*)d_in[19];

    const int* src = edge_index;             // edge_index[0, :]
    const int* dst = edge_index + N_EDGES;   // edge_index[1, :]

    // ---- workspace bump allocator (~41 MB) ----
    char* p = (char*)d_ws;
    auto alloc = [&](size_t bytes) {
        char* r = p;
        p += (bytes + 255) & ~(size_t)255;
        return (void*)r;
    };
    bf16*  HsA    = (bf16*) alloc((size_t)N_NODES * 64 * 2);
    bf16*  HsB    = (bf16*) alloc((size_t)N_NODES * 64 * 2);
    int*   hist   = (int*)  alloc((size_t)N_NODES * 4);
    int*   offs   = (int*)  alloc((size_t)N_NODES * 4);
    float* dinv   = (float*)alloc((size_t)N_NODES * 4);
    int*   ssrc   = (int*)  alloc((size_t)N_EDGES * 4);
    unsigned int* packed = (unsigned int*)alloc((size_t)N_EDGES * 4);
    int*   tileCnt   = (int*)alloc((size_t)NBUCKET * NT * 4);
    int*   bucketTot = (int*)alloc((size_t)NBUCKET * 4);
    float* pooled = (float*)alloc((size_t)N_GRAPHS * 256 * 4);

    hipMemsetAsync(pooled, 0, (size_t)N_GRAPHS * 256 * 4, stream);

    // deterministic bucketed counting sort (no global atomics anywhere)
    k_bucket_count<<<NT, 256, 0, stream>>>(dst, tileCnt, N_EDGES);
    k_tile_scan<<<NBUCKET, 256, 0, stream>>>(tileCnt, bucketTot);
    k_scan_sums<<<1, 512, 0, stream>>>(bucketTot, NBUCKET);       // -> bucket bases
    k_bucket_write<<<NT, 256, 0, stream>>>(src, dst, bucketTot, tileCnt, packed, N_EDGES);
    k_local_sort<<<NBUCKET, 256, 0, stream>>>(packed, bucketTot, ssrc, offs, hist,
                                              dinv, N_NODES, N_EDGES);

    const int mmTiles  = N_NODES / 16;           // 6250 (16 | 100000)
    const int mmBlocks = 512;
    const int mmWaves  = mmBlocks * 4;

    // layer-0 matmul from x
    k_matmul_mfma<<<mmBlocks, 256, 0, stream>>>(x, Wl[0], dinv, HsA, mmTiles, mmWaves);

    // layers 0-2: fused gather+MFMA (ping-pong), layer 3: lean gather
    bf16* hsIn[3]  = { HsA, HsB, HsA };
    bf16* hsOut[3] = { HsB, HsA, HsB };
    for (int layer = 0; layer < 3; layer++) {
        k_gather_mm<<<2048, 256, 0, stream>>>(
            hsIn[layer], ssrc, offs, hist, dinv, bl[layer],
            bn_gamma + layer * 64, bn_beta + layer * 64,
            bn_mean + layer * 64, bn_var + layer * 64,
            batch, Wl[layer + 1], hsOut[layer], pooled, layer, mmTiles);
    }
    k_gather<<<4096, 256, 0, stream>>>(
        HsB, ssrc, offs, hist, dinv, bl[3],
        bn_gamma + 3 * 64, bn_beta + 3 * 64,
        bn_mean + 3 * 64, bn_var + 3 * 64,
        batch, pooled, 3, N_NODES, 4096 * 4);

    k_mlp<<<N_GRAPHS, 64, 0, stream>>>(pooled, lin1_W, lin1_b, lin2_W, lin2_b,
                                       (float*)d_out);
}

// Round 18
// 369.631 us; speedup vs baseline: 1.1930x; 1.1930x over previous
//
#include <hip/hip_runtime.h>
#include <hip/hip_bf16.h>

#define N_NODES   100000
#define N_EDGES   1600000
#define DIM       64
#define OUT_DIM   10
#define N_GRAPHS  1000
#define BN_EPS    1e-5f
#define NBUCKET   391          // ceil(N_NODES / 256)
#define TILE_E    6400
#define NT        250          // N_EDGES / TILE_E (exact)

typedef __hip_bfloat16 bf16;
__device__ __forceinline__ float b2f(bf16 v) { return __bfloat162float(v); }

typedef __attribute__((ext_vector_type(8))) short short8;   // 8 bf16 = 4 VGPRs
typedef __attribute__((ext_vector_type(4))) float floatx4;  // MFMA C/D

__device__ __forceinline__ short f2bs(float f) {
    union { bf16 h; short s; } u;
    u.h = __float2bfloat16(f);
    return u.s;
}

// ---- phase 1: per-tile bucket histogram (LDS atomics only) ----

__global__ void __launch_bounds__(256) k_bucket_count(const int* __restrict__ dst,
                                                      int* __restrict__ tileCnt, int e) {
    __shared__ int hcnt[NBUCKET];
    int t = blockIdx.x, tid = threadIdx.x;
    for (int b = tid; b < NBUCKET; b += 256) hcnt[b] = 0;
    __syncthreads();
    int ibase = t * TILE_E;
    for (int j = 0; j < TILE_E; j += 256) {
        int i = ibase + j + tid;
        if (i < e) atomicAdd(&hcnt[dst[i] >> 8], 1);
    }
    __syncthreads();
    for (int b = tid; b < NBUCKET; b += 256) tileCnt[b * NT + t] = hcnt[b];
}

// ---- phase 2a: per-bucket exclusive scan over tiles (in-place) + bucket totals ----

__global__ void __launch_bounds__(256) k_tile_scan(int* __restrict__ tileCnt,
                                                   int* __restrict__ bucketTot) {
    __shared__ int tmp[256];
    int b = blockIdx.x, tid = threadIdx.x;
    int v = (tid < NT) ? tileCnt[b * NT + tid] : 0;
    tmp[tid] = v;
    __syncthreads();
    for (int off = 1; off < 256; off <<= 1) {
        int t = (tid >= off) ? tmp[tid - off] : 0;
        __syncthreads();
        tmp[tid] += t;
        __syncthreads();
    }
    if (tid < NT) tileCnt[b * NT + tid] = tmp[tid] - v;   // exclusive over tiles
    if (tid == 255) bucketTot[b] = tmp[255];
}

// ---- phase 2b: single-block exclusive scan of bucket totals (nb <= 512) ----

__global__ void k_scan_sums(int* __restrict__ bsums, int nb) {
    __shared__ int tmp[512];
    int tid = threadIdx.x;
    int v = (tid < nb) ? bsums[tid] : 0;
    tmp[tid] = v;
    __syncthreads();
    for (int off = 1; off < 512; off <<= 1) {
        int t = (tid >= off) ? tmp[tid - off] : 0;
        __syncthreads();
        tmp[tid] += t;
        __syncthreads();
    }
    if (tid < nb) bsums[tid] = tmp[tid] - v;      // exclusive -> bucket base
}

// ---- phase 3: write edges into per-tile reserved ranges (dense, no global atomics) ----

__global__ void __launch_bounds__(256) k_bucket_write(
    const int* __restrict__ src, const int* __restrict__ dst,
    const int* __restrict__ bbase, const int* __restrict__ tilePrefix,
    unsigned int* __restrict__ packed, int e) {
    __shared__ int hbase[NBUCKET];
    __shared__ int hcur[NBUCKET];
    int t = blockIdx.x, tid = threadIdx.x;
    for (int b = tid; b < NBUCKET; b += 256) {
        hbase[b] = bbase[b] + tilePrefix[b * NT + t];
        hcur[b] = 0;
    }
    __syncthreads();
    int ibase = t * TILE_E;
    for (int j = 0; j < TILE_E; j += 256) {
        int i = ibase + j + tid;
        if (i < e) {
            int d  = dst[i];
            int bb = d >> 8;
            int pos = hbase[bb] + atomicAdd(&hcur[bb], 1);
            packed[pos] = ((unsigned int)src[i] << 8) | (unsigned int)(d & 255);
        }
    }
}

// ---- phase 4: within-bucket counting sort; also emits offs/hist/dinv ----

__global__ void __launch_bounds__(256) k_local_sort(
    const unsigned int* __restrict__ packed, const int* __restrict__ bbase,
    int* __restrict__ ssrc, int* __restrict__ offs, int* __restrict__ hist,
    float* __restrict__ dinv, int n, int e) {
    __shared__ int tmp[256];
    __shared__ int noffs[256];
    __shared__ int ncur[256];
    int b = blockIdx.x, tid = threadIdx.x;
    int base   = b << 8;
    int estart = bbase[b];
    int eend   = (b + 1 < NBUCKET) ? bbase[b + 1] : e;

    ncur[tid] = 0;                 // reuse as per-node counter first
    __syncthreads();
    for (int i = estart + tid; i < eend; i += 256)
        atomicAdd(&ncur[packed[i] & 255u], 1);
    __syncthreads();
    int v = ncur[tid];             // degree of node base+tid
    tmp[tid] = v;
    __syncthreads();
    for (int off = 1; off < 256; off <<= 1) {
        int t = (tid >= off) ? tmp[tid - off] : 0;
        __syncthreads();
        tmp[tid] += t;
        __syncthreads();
    }
    int mystart = estart + tmp[tid] - v;   // exclusive within bucket
    noffs[tid] = mystart;
    ncur[tid]  = 0;
    int node = base + tid;
    if (node < n) {
        offs[node] = mystart;
        hist[node] = v;
        dinv[node] = rsqrtf((float)(v + 1));   // +1 self loop
    }
    __syncthreads();
    for (int i = estart + tid; i < eend; i += 256) {
        unsigned int p = packed[i];
        int d = p & 255u;
        int pos = noffs[d] + atomicAdd(&ncur[d], 1);
        ssrc[pos] = (int)(p >> 8);
    }
}

// ------- MFMA matmul: Hs[row] = dinv[row] * (h[row] @ W) -> bf16 (R15-proven) -------
// Verified layouts (m89/m91/m120): A[m=lane&15][k=quad*8+j] (contiguous 16B),
// B[k=quad*8+j][n=lane&15], C/D[row=quad*4+reg][col=lane&15].

__global__ void __launch_bounds__(256) k_matmul_mfma(
    const float* __restrict__ hf, const bf16* __restrict__ hb, int use_f32,
    const float* __restrict__ W, const float* __restrict__ dinv,
    bf16* __restrict__ Hs, int ntiles, int nwaves)
{
    int wid  = (blockIdx.x * blockDim.x + threadIdx.x) >> 6;
    int lane = threadIdx.x & 63;
    int quad = lane >> 4, m16 = lane & 15;

    short8 Bfrag[4][2];
#pragma unroll
    for (int t = 0; t < 4; t++)
#pragma unroll
        for (int h = 0; h < 2; h++) {
            short8 b;
#pragma unroll
            for (int j = 0; j < 8; j++)
                b[j] = f2bs(W[(h * 32 + quad * 8 + j) * 64 + t * 16 + m16]);
            Bfrag[t][h] = b;
        }

    for (int tile = wid; tile < ntiles; tile += nwaves) {
        int row0 = tile * 16;
        short8 A0, A1;
        if (use_f32) {
            const float* base = hf + (size_t)(row0 + m16) * 64 + quad * 8;
#pragma unroll
            for (int j = 0; j < 8; j++) {
                A0[j] = f2bs(base[j]);
                A1[j] = f2bs(base[32 + j]);
            }
        } else {
            const short* base = (const short*)hb + (size_t)(row0 + m16) * 64 + quad * 8;
            A0 = *(const short8*)(base);
            A1 = *(const short8*)(base + 32);
        }

        floatx4 acc[4];
#pragma unroll
        for (int t = 0; t < 4; t++) {
            floatx4 c = {0.f, 0.f, 0.f, 0.f};
            c = __builtin_amdgcn_mfma_f32_16x16x32_bf16(A0, Bfrag[t][0], c, 0, 0, 0);
            c = __builtin_amdgcn_mfma_f32_16x16x32_bf16(A1, Bfrag[t][1], c, 0, 0, 0);
            acc[t] = c;
        }

#pragma unroll
        for (int r = 0; r < 4; r++) {
            int row = row0 + quad * 4 + r;
            float dn = dinv[row];
#pragma unroll
            for (int t = 0; t < 4; t++)
                Hs[(size_t)row * 64 + t * 16 + m16] = __float2bfloat16(dn * acc[t][r]);
        }
    }
}

// ------- gather + BN + relu + JK-pool (R15 inner loop + chunked pooled accum) -------
// batch[] is sorted: a wave owning a CONTIGUOUS node chunk crosses a graph
// boundary rarely -> accumulate pooled contribution in a register and flush
// on boundary change (R15 profile: 25.6MB of the 37.5MB WRITE_SIZE was
// 6.4M cross-XCD pooled atomics; this cuts them ~6x). Index/batch loads stay
// wave-uniform -> scalar SMEM.

__global__ void __launch_bounds__(256) k_gather(
    const bf16* __restrict__ Hs, const int* __restrict__ ssrc,
    const int* __restrict__ offs, const int* __restrict__ hist,
    const float* __restrict__ dinv, const float* __restrict__ bias,
    const float* __restrict__ gamma, const float* __restrict__ beta,
    const float* __restrict__ mean, const float* __restrict__ var,
    const int* __restrict__ batch, bf16* __restrict__ hout,
    float* __restrict__ pooled, int layer, int n, int nwaves)
{
    int wid  = (blockIdx.x * blockDim.x + threadIdx.x) >> 6;   // global wave id
    int lane = threadIdx.x & 63;

    float P = gamma[lane] * rsqrtf(var[lane] + BN_EPS);
    float Q = (bias[lane] - mean[lane]) * P + beta[lane];

    int chunk = (n + nwaves - 1) / nwaves;        // contiguous nodes per wave
    int node0 = wid * chunk;
    int node1 = min(node0 + chunk, n);

    float pacc = 0.f;
    int   curg = -1;

    for (int node = node0; node < node1; node++) {
        int start = __builtin_amdgcn_readfirstlane(offs[node]);
        int cnt   = __builtin_amdgcn_readfirstlane(hist[node]);

        float acc = b2f(Hs[node * 64 + lane]);    // self-loop term (pre-scaled)
        int i = 0;
        for (; i + 15 < cnt; i += 16) {
            int s0  = ssrc[start + i];
            int s1  = ssrc[start + i + 1];
            int s2  = ssrc[start + i + 2];
            int s3  = ssrc[start + i + 3];
            int s4  = ssrc[start + i + 4];
            int s5  = ssrc[start + i + 5];
            int s6  = ssrc[start + i + 6];
            int s7  = ssrc[start + i + 7];
            int s8  = ssrc[start + i + 8];
            int s9  = ssrc[start + i + 9];
            int s10 = ssrc[start + i + 10];
            int s11 = ssrc[start + i + 11];
            int s12 = ssrc[start + i + 12];
            int s13 = ssrc[start + i + 13];
            int s14 = ssrc[start + i + 14];
            int s15 = ssrc[start + i + 15];
            float v0  = b2f(Hs[s0  * 64 + lane]);
            float v1  = b2f(Hs[s1  * 64 + lane]);
            float v2  = b2f(Hs[s2  * 64 + lane]);
            float v3  = b2f(Hs[s3  * 64 + lane]);
            float v4  = b2f(Hs[s4  * 64 + lane]);
            float v5  = b2f(Hs[s5  * 64 + lane]);
            float v6  = b2f(Hs[s6  * 64 + lane]);
            float v7  = b2f(Hs[s7  * 64 + lane]);
            float v8  = b2f(Hs[s8  * 64 + lane]);
            float v9  = b2f(Hs[s9  * 64 + lane]);
            float v10 = b2f(Hs[s10 * 64 + lane]);
            float v11 = b2f(Hs[s11 * 64 + lane]);
            float v12 = b2f(Hs[s12 * 64 + lane]);
            float v13 = b2f(Hs[s13 * 64 + lane]);
            float v14 = b2f(Hs[s14 * 64 + lane]);
            float v15 = b2f(Hs[s15 * 64 + lane]);
            acc += (((v0 + v1) + (v2 + v3)) + ((v4 + v5) + (v6 + v7))) +
                   (((v8 + v9) + (v10 + v11)) + ((v12 + v13) + (v14 + v15)));
        }
        for (; i + 7 < cnt; i += 8) {
            int s0 = ssrc[start + i];
            int s1 = ssrc[start + i + 1];
            int s2 = ssrc[start + i + 2];
            int s3 = ssrc[start + i + 3];
            int s4 = ssrc[start + i + 4];
            int s5 = ssrc[start + i + 5];
            int s6 = ssrc[start + i + 6];
            int s7 = ssrc[start + i + 7];
            float v0 = b2f(Hs[s0 * 64 + lane]);
            float v1 = b2f(Hs[s1 * 64 + lane]);
            float v2 = b2f(Hs[s2 * 64 + lane]);
            float v3 = b2f(Hs[s3 * 64 + lane]);
            float v4 = b2f(Hs[s4 * 64 + lane]);
            float v5 = b2f(Hs[s5 * 64 + lane]);
            float v6 = b2f(Hs[s6 * 64 + lane]);
            float v7 = b2f(Hs[s7 * 64 + lane]);
            acc += ((v0 + v1) + (v2 + v3)) + ((v4 + v5) + (v6 + v7));
        }
        for (; i + 3 < cnt; i += 4) {
            int s0 = ssrc[start + i];
            int s1 = ssrc[start + i + 1];
            int s2 = ssrc[start + i + 2];
            int s3 = ssrc[start + i + 3];
            float v0 = b2f(Hs[s0 * 64 + lane]);
            float v1 = b2f(Hs[s1 * 64 + lane]);
            float v2 = b2f(Hs[s2 * 64 + lane]);
            float v3 = b2f(Hs[s3 * 64 + lane]);
            acc += (v0 + v1) + (v2 + v3);
        }
        for (; i < cnt; i++)
            acc += b2f(Hs[ssrc[start + i] * 64 + lane]);

        float val = fmaxf(dinv[node] * acc * P + Q, 0.f);

        int g = __builtin_amdgcn_readfirstlane(batch[node]);
        if (g != curg) {
            if (curg >= 0)
                atomicAdd(&pooled[curg * 256 + layer * 64 + lane], pacc);
            pacc = 0.f;
            curg = g;
        }
        pacc += val;

        if (hout) hout[node * 64 + lane] = __float2bfloat16(val);
    }
    if (curg >= 0)
        atomicAdd(&pooled[curg * 256 + layer * 64 + lane], pacc);
}

// ---------------- final MLP: relu(pooled@W1+b1)@W2+b2 -> f32 out ----------------

__global__ void k_mlp(const float* __restrict__ pooled, const float* __restrict__ W1,
                      const float* __restrict__ b1, const float* __restrict__ W2,
                      const float* __restrict__ b2, float* __restrict__ out) {
    __shared__ float p[256];
    __shared__ float t[64];
    int g = blockIdx.x;
    int tid = threadIdx.x;    // 64 threads
    for (int i = tid; i < 256; i += 64) p[i] = pooled[g * 256 + i];
    __syncthreads();
    float acc = b1[tid];
    for (int k = 0; k < 256; k++)
        acc = fmaf(p[k], W1[k * 64 + tid], acc);
    t[tid] = fmaxf(acc, 0.f);
    __syncthreads();
    if (tid < OUT_DIM) {
        float o = b2[tid];
#pragma unroll
        for (int d = 0; d < 64; d++)
            o = fmaf(t[d], W2[d * OUT_DIM + tid], o);
        out[g * OUT_DIM + tid] = o;
    }
}

// ---------------- host launch ----------------

extern "C" void kernel_launch(void* const* d_in, const int* in_sizes, int n_in,
                              void* d_out, int out_size, void* d_ws, size_t ws_size,
                              hipStream_t stream) {
    const float* x          = (const float*)d_in[0];
    const int*   edge_index = (const int*)d_in[1];
    const int*   batch      = (const int*)d_in[2];
    const float* Wl[4] = { (const float*)d_in[4], (const float*)d_in[6],
                           (const float*)d_in[8], (const float*)d_in[10] };
    const float* bl[4] = { (const float*)d_in[5], (const float*)d_in[7],
                           (const float*)d_in[9], (const float*)d_in[11] };
    const float* bn_gamma = (const float*)d_in[12];
    const float* bn_beta  = (const float*)d_in[13];
    const float* bn_mean  = (const float*)d_in[14];
    const float* bn_var   = (const float*)d_in[15];
    const float* lin1_W = (const float*)d_in[16];
    const float* lin1_b = (const float*)d_in[17];
    const float* lin2_W = (const float*)d_in[18];
    const float* lin2_b = (const float*)d_in[19];

    const int* src = edge_index;             // edge_index[0, :]
    const int* dst = edge_index + N_EDGES;   // edge_index[1, :]

    // ---- workspace bump allocator (~41 MB) ----
    char* p = (char*)d_ws;
    auto alloc = [&](size_t bytes) {
        char* r = p;
        p += (bytes + 255) & ~(size_t)255;
        return (void*)r;
    };
    bf16*  Hs     = (bf16*) alloc((size_t)N_NODES * 64 * 2);
    bf16*  hbuf   = (bf16*) alloc((size_t)N_NODES * 64 * 2);
    int*   hist   = (int*)  alloc((size_t)N_NODES * 4);
    int*   offs   = (int*)  alloc((size_t)N_NODES * 4);
    float* dinv   = (float*)alloc((size_t)N_NODES * 4);
    int*   ssrc   = (int*)  alloc((size_t)N_EDGES * 4);
    unsigned int* packed = (unsigned int*)alloc((size_t)N_EDGES * 4);
    int*   tileCnt   = (int*)alloc((size_t)NBUCKET * NT * 4);
    int*   bucketTot = (int*)alloc((size_t)NBUCKET * 4);
    float* pooled = (float*)alloc((size_t)N_GRAPHS * 256 * 4);

    hipMemsetAsync(pooled, 0, (size_t)N_GRAPHS * 256 * 4, stream);

    // deterministic bucketed counting sort (no global atomics anywhere)
    k_bucket_count<<<NT, 256, 0, stream>>>(dst, tileCnt, N_EDGES);
    k_tile_scan<<<NBUCKET, 256, 0, stream>>>(tileCnt, bucketTot);
    k_scan_sums<<<1, 512, 0, stream>>>(bucketTot, NBUCKET);       // -> bucket bases
    k_bucket_write<<<NT, 256, 0, stream>>>(src, dst, bucketTot, tileCnt, packed, N_EDGES);
    k_local_sort<<<NBUCKET, 256, 0, stream>>>(packed, bucketTot, ssrc, offs, hist,
                                              dinv, N_NODES, N_EDGES);

    const int mmTiles  = N_NODES / 16;           // 6250 (16 | 100000)
    const int mmBlocks = 512;
    const int mmWaves  = mmBlocks * 4;

    // layer-0 matmul from x (f32 path), then alternate lean-gather / MFMA-matmul
    k_matmul_mfma<<<mmBlocks, 256, 0, stream>>>(x, (const bf16*)nullptr, 1,
                                                Wl[0], dinv, Hs, mmTiles, mmWaves);

    const int gatherBlocks = 4096;               // 16384 waves, chunk = 7 nodes
    const int nwaves = gatherBlocks * 4;
    for (int layer = 0; layer < 4; layer++) {
        bf16* hout = (layer < 3) ? hbuf : (bf16*)nullptr;
        k_gather<<<gatherBlocks, 256, 0, stream>>>(
            Hs, ssrc, offs, hist, dinv, bl[layer],
            bn_gamma + layer * 64, bn_beta + layer * 64,
            bn_mean + layer * 64, bn_var + layer * 64,
            batch, hout, pooled, layer, N_NODES, nwaves);
        if (layer < 3)
            k_matmul_mfma<<<mmBlocks, 256, 0, stream>>>((const float*)nullptr, hbuf, 0,
                                                        Wl[layer + 1], dinv, Hs,
                                                        mmTiles, mmWaves);
    }

    k_mlp<<<N_GRAPHS, 64, 0, stream>>>(pooled, lin1_W, lin1_b, lin2_W, lin2_b,
                                       (float*)d_out);
}